// Round 7
// baseline (243.952 us; speedup 1.0000x reference)
//
#include <hip/hip_runtime.h>
#include <math.h>

#define DIMS   256
#define KCODES 1024
#define NTOT   32768
#define TAU    4.0e-4f   // 3-term split distance-compare error <~6e-5; 6x margin

typedef __bf16 bf16x8 __attribute__((ext_vector_type(8)));
typedef float  f32x4  __attribute__((ext_vector_type(4)));

// ---- workspace layout (float indices; int views share) ----
#define WS_COMMIT   0          // float atomic
#define WS_FLAGCNT  1          // int atomic
#define WS_DECORR   2          // float atomic
#define WS_COLSUM   16         // float[256]  (direct-stored by cov blocks)
#define WS_COLSQ    272        // float[256]  (direct-stored by cov blocks)
#define WS_WSQ      1024       // float[1024]  (direct-stored by W-pack blocks)
#define WS_XSQ      2048       // float[32768] (direct-stored by X-pack blocks)
// memset zero region: bytes [0, 12) only (COMMIT, FLAGCNT, DECORR)
#define WS_FLAGS    34816      // int[32768]
#define WS_CAND1    67584      // float[8*32768] (slots 0..3 used)
#define WS_CAND2    329728     // float[8*32768]
#define WS_CANDI    591872     // int[8*32768]
#define WS_WP       854016     // bf16[524288] = 1 MB, fragment-ordered W

// ---- output layout (floats) ----
#define OUT_Q    0
#define OUT_IDX  8388608
#define OUT_SCAL 8421376

// Fragment layout (both Xp and Wp2), bf16 elems:
//   frag(bt, kt, wv, t, hl) base = ((((bt*8+kt)*2+wv)*4+t)*2+hl)*512
//   element (lane = kq*16+lc, e) at base + lane*8 + e
//   holds hi/lo bf16 of src[row = bt*128+wv*64+t*16+lc][k = kt*32+kq*8+e]
// => for fixed (bt,kt) the 16 frags are 8192 contiguous elems (16 KB).

// ---------- fused prep ----------
// blocks [0,1024): pack X | [1024,1056): pack W | [1056,1312): cov+colstats
__global__ __launch_bounds__(256) void prep_kernel(const float* __restrict__ X,
                                                   const float* __restrict__ W,
                                                   __bf16* __restrict__ Xp,
                                                   __bf16* __restrict__ Wp2,
                                                   float* ws) {
  int b = blockIdx.x;
  int tid = threadIdx.x;
  if (b < 1056) {
    __shared__ float sqred[256];
    bool isW = b >= 1024;
    const float* src = isW ? W : X;
    __bf16* dst = isW ? Wp2 : Xp;
    int sqoff = isW ? WS_WSQ : WS_XSQ;
    int bb = isW ? b - 1024 : b;
    int kt = tid >> 5, mtl = (tid >> 4) & 1, lc = tid & 15;
    int row = bb * 32 + mtl * 16 + lc;
    int bt = row >> 7, c = row & 127;
    int wv = c >> 6, t = (c >> 4) & 3;
    size_t hibase = ((((size_t)(bt * 8 + kt) * 2 + wv) * 4 + t) * 2) * 512;
    const float* s = src + (size_t)row * DIMS + kt * 32;
    float sq = 0.f;
    #pragma unroll
    for (int kq = 0; kq < 4; kq++) {
      float4 u = *(const float4*)(s + kq * 8);
      float4 v = *(const float4*)(s + kq * 8 + 4);
      float f[8] = {u.x, u.y, u.z, u.w, v.x, v.y, v.z, v.w};
      bf16x8 hi, lo;
      #pragma unroll
      for (int e = 0; e < 8; e++) {
        __bf16 h = (__bf16)f[e];
        hi[e] = h;
        lo[e] = (__bf16)(f[e] - (float)h);
        sq = fmaf(f[e], f[e], sq);
      }
      size_t off = (size_t)(kq * 16 + lc) * 8;
      *(bf16x8*)&dst[hibase + off] = hi;
      *(bf16x8*)&dst[hibase + 512 + off] = lo;
    }
    // block-owned row-norm reduce (rows bb*32..bb*32+31)
    sqred[tid] = sq;
    __syncthreads();
    if (tid < 32) {
      float s8 = 0.f;
      #pragma unroll
      for (int k = 0; k < 8; k++) s8 += sqred[k * 32 + tid];
      ws[sqoff + bb * 32 + tid] = s8;
    }
  } else {
    // cov + colstats: 256 blocks x 1 column, self-contained means
    __shared__ float wi_s[KCODES];
    __shared__ float red2[256];
    __shared__ float miB;
    __shared__ float red[4];
    int i0 = b - 1056;
    #pragma unroll
    for (int q = 0; q < 4; q++) {
      int row = q * 256 + tid;
      wi_s[row] = W[(size_t)row * DIMS + i0];
    }
    __syncthreads();
    float pm = 0.f;
    #pragma unroll
    for (int q = 0; q < 4; q++) pm += wi_s[tid * 4 + q];
    red2[tid] = pm;
    __syncthreads();
    if (tid == 0) {
      float s = 0.f;
      for (int k = 0; k < 256; k++) s += red2[k];
      miB = s * (1.0f / 1024.0f);
    }
    int j = tid;
    float a0 = 0.f, sj = 0.f, sqj = 0.f;
    for (int k = 0; k < KCODES; k += 4) {
      #pragma unroll
      for (int u = 0; u < 4; u++) {
        float wj = W[(size_t)(k + u) * DIMS + j];
        a0 = fmaf(wi_s[k + u], wj, a0);
        sj += wj;
        sqj = fmaf(wj, wj, sqj);
      }
    }
    if (j == i0) {
      ws[WS_COLSUM + i0] = sj;
      ws[WS_COLSQ + i0] = sqj;
    }
    __syncthreads();  // miB ready
    const float inv = 1.0f / 1024.0f;
    float mj = sj * inv;
    float v = 0.f;
    float c0 = a0 * inv - miB * mj;
    if (i0 != j) v = c0 * c0;
    #pragma unroll
    for (int m = 32; m >= 1; m >>= 1) v += __shfl_xor(v, m);
    if ((j & 63) == 0) red[j >> 6] = v;
    __syncthreads();
    if (j == 0) atomicAdd(&ws[WS_DECORR], (red[0] + red[1]) + (red[2] + red[3]));
  }
}

// ---------- pass1 v7: v6 + TRUE counted vmcnt (T4) — queue never drains ----------
// v6 reproduced m218's "8-phase with drain0 == 1-phase" null exactly (85 us).
// Fix per m218: group staged pieces by consumption deadline and wait with
// counted immediates so staging loads stay in flight across barriers.
//   pieces: 0=A(c0,h0) 1=A(c0,h1) 2=A(c1,h0) 3=A(c1,h1) 4..7=B
//   reads:  p0/p1 consume B(4..7) + A h0 pieces {0,2}; p2/p3 consume h1 {1,3}
//   G0 = {4,5,6,7,0,2} (6 loads, deadline kt p0), G1 = {1,3} (2 loads, p2)
//   issue: p0 {4,5,6}, p1 {7,0,2}, p2 {1,3}  (FIFO: all G0 before G1)
//   waits: end-p1 vmcnt(6)  -> retires G1(kt), leaves G0(kt+1) in flight
//          end-p3 vmcnt(2)  -> retires G0(kt+1), leaves G1(kt+1) in flight
//   kt=7: end-p1 vmcnt(0) (no new issues). Lead time >= 2 phases (~2000 cyc).
// All other structure/numerics identical to v6 -> bit-identical results.
__device__ __forceinline__ void stage16(const __bf16* g, __bf16* l) {
  __builtin_amdgcn_global_load_lds(
      (const __attribute__((address_space(1))) void*)g,
      (__attribute__((address_space(3))) void*)l, 16, 0, 0);
}

// slot layout (bf16 elems): A [c][h][4096] at 0..16384, B same at 16384..32768
#define STAGE_PIECE(T, J) do {                                                      \
    __bf16* _d = buf + ((T) & 1) * 32768;                                           \
    if ((J) < 4) {                                                                  \
      int _c = (J) >> 1, _h = (J) & 1;                                              \
      stage16(Xp + (size_t)(bm * 2 + _c) * 65536 + (size_t)(T) * 8192 + _h * 4096 + tid * 8, \
              _d + _c * 8192 + _h * 4096 + tid * 8);                                \
    } else {                                                                        \
      int _c = ((J) - 4) >> 1, _h = (J) & 1;                                        \
      stage16(Wp2 + (size_t)(bn * 2 + _c) * 65536 + (size_t)(T) * 8192 + _h * 4096 + tid * 8, \
              _d + 16384 + _c * 8192 + _h * 4096 + tid * 8);                        \
    }                                                                               \
  } while (0)

__global__ __launch_bounds__(512, 1) void pass1_kernel(const __bf16* __restrict__ Xp,
                                                       const __bf16* __restrict__ Wp2,
                                                       float* ws) {
  __shared__ __align__(16) __bf16 buf[65536];  // 2 slots x 32768 elems = 128 KB
  __shared__ float wsqs[256];
  __shared__ float d1L[256][4];
  __shared__ float d2L[256][4];
  __shared__ int   i1L[256][4];

  int tid = threadIdx.x;
  int lane = tid & 63, wave = tid >> 6;
  int wm = wave >> 2, wn = wave & 3;   // wm: 128-row strip 0..1, wn: 64-col strip 0..3
  int quad = lane >> 4, col = lane & 15;
  int l = blockIdx.x;
  // L2-window swizzle: XCD x (l&7) runs j=0..63; window = 8 bm x 4 bn = 32
  // concurrent blocks (=32 CUs/XCD), footprint 2MB A + 1MB B < 4MB L2.
  int x = l & 7;
  int j = l >> 3;                        // 0..63
  int bm = x * 16 + (j & 7) + (j >> 5) * 8;   // 0..127
  int bn = (j >> 3) & 3;                 // 0..3
  int cb = bn * 256;

  f32x4 acc[8][4];
  #pragma unroll
  for (int i = 0; i < 8; i++)
    #pragma unroll
    for (int jj = 0; jj < 4; jj++) acc[i][jj] = (f32x4){0.f, 0.f, 0.f, 0.f};

  wsqs[tid & 255] = ws[WS_WSQ + cb + (tid & 255)];  // dup writes benign

  // prologue: stage tile 0 (G0 then G1 order), drain, barrier
  STAGE_PIECE(0, 4); STAGE_PIECE(0, 5); STAGE_PIECE(0, 6); STAGE_PIECE(0, 7);
  STAGE_PIECE(0, 0); STAGE_PIECE(0, 2); STAGE_PIECE(0, 1); STAGE_PIECE(0, 3);
  asm volatile("s_waitcnt vmcnt(0)" ::: "memory");
  __builtin_amdgcn_s_barrier();

  #pragma unroll
  for (int kt = 0; kt < 8; kt++) {
    const __bf16* sl = buf + (kt & 1) * 32768;
    const __bf16* bA = sl + wm * 8192 + lane * 8;
    const __bf16* bB = sl + 16384 + (wn >> 1) * 8192 + (wn & 1) * 4096 + lane * 8;
    bf16x8 Bf[4][2];
    #pragma unroll
    for (int p = 0; p < 4; p++) {
      // --- ds_reads for this phase (from slot kt&1) ---
      if (p == 0) {
        #pragma unroll
        for (int nt = 0; nt < 4; nt++) {
          Bf[nt][0] = *(const bf16x8*)(bB + nt * 1024);
          Bf[nt][1] = *(const bf16x8*)(bB + nt * 1024 + 512);
        }
      }
      bf16x8 A0a = *(const bf16x8*)(bA + (2 * p + 0) * 1024);
      bf16x8 A0b = *(const bf16x8*)(bA + (2 * p + 0) * 1024 + 512);
      bf16x8 A1a = *(const bf16x8*)(bA + (2 * p + 1) * 1024);
      bf16x8 A1b = *(const bf16x8*)(bA + (2 * p + 1) * 1024 + 512);
      // --- counted stage-issue of kt+1: G0 at p0/p1, G1 at p2 (FIFO order) ---
      if (kt < 7) {
        if (p == 0) { STAGE_PIECE(kt + 1, 4); STAGE_PIECE(kt + 1, 5);
                      STAGE_PIECE(kt + 1, 6); }
        if (p == 1) { STAGE_PIECE(kt + 1, 7); STAGE_PIECE(kt + 1, 0);
                      STAGE_PIECE(kt + 1, 2); }
        if (p == 2) { STAGE_PIECE(kt + 1, 1); STAGE_PIECE(kt + 1, 3); }
      }
      // --- phase body: barrier, wait reads, fenced MFMA cluster, barrier ---
      __builtin_amdgcn_s_barrier();
      asm volatile("s_waitcnt lgkmcnt(0)" ::: "memory");
      __builtin_amdgcn_sched_barrier(0);  // rule #18: pin MFMAs below the wait
      __builtin_amdgcn_s_setprio(1);
      #pragma unroll
      for (int nt = 0; nt < 4; nt++) {
        acc[2 * p + 0][nt] = __builtin_amdgcn_mfma_f32_16x16x32_bf16(A0a, Bf[nt][0], acc[2 * p + 0][nt], 0, 0, 0);
        acc[2 * p + 0][nt] = __builtin_amdgcn_mfma_f32_16x16x32_bf16(A0a, Bf[nt][1], acc[2 * p + 0][nt], 0, 0, 0);
        acc[2 * p + 0][nt] = __builtin_amdgcn_mfma_f32_16x16x32_bf16(A0b, Bf[nt][0], acc[2 * p + 0][nt], 0, 0, 0);
        acc[2 * p + 1][nt] = __builtin_amdgcn_mfma_f32_16x16x32_bf16(A1a, Bf[nt][0], acc[2 * p + 1][nt], 0, 0, 0);
        acc[2 * p + 1][nt] = __builtin_amdgcn_mfma_f32_16x16x32_bf16(A1a, Bf[nt][1], acc[2 * p + 1][nt], 0, 0, 0);
        acc[2 * p + 1][nt] = __builtin_amdgcn_mfma_f32_16x16x32_bf16(A1b, Bf[nt][0], acc[2 * p + 1][nt], 0, 0, 0);
      }
      __builtin_amdgcn_s_setprio(0);
      // --- counted waits (never drain in steady state) ---
      if (p == 1) {
        if (kt < 7) asm volatile("s_waitcnt vmcnt(6)" ::: "memory");  // G1(kt) landed
        else        asm volatile("s_waitcnt vmcnt(0)" ::: "memory");  // tail
      }
      if (p == 3 && kt < 7)
        asm volatile("s_waitcnt vmcnt(2)" ::: "memory");              // G0(kt+1) landed
      __builtin_amdgcn_s_barrier();
    }
  }

  // epilogue: per-row (best, 2nd, idx); C layout: row = quad*4 + reg, col = lane&15
  #pragma unroll
  for (int mt = 0; mt < 8; mt++) {
    #pragma unroll
    for (int r = 0; r < 4; r++) {
      float d1 = 3.0e38f, d2 = 3.0e38f;
      int i1 = 0;
      #pragma unroll
      for (int nt = 0; nt < 4; nt++) {
        int lc = wn * 64 + nt * 16 + col;
        float d = wsqs[lc] - 2.0f * acc[mt][nt][r];
        int g = cb + lc;
        if (d < d1) { d2 = d1; d1 = d; i1 = g; }
        else if (d < d2) d2 = d;
      }
      #pragma unroll
      for (int m = 1; m < 16; m <<= 1) {
        float od1 = __shfl_xor(d1, m);
        int oi1 = __shfl_xor(i1, m);
        float od2 = __shfl_xor(d2, m);
        if (od1 < d1 || (od1 == d1 && oi1 < i1)) {
          d2 = fminf(d1, fminf(d2, od2));
          d1 = od1; i1 = oi1;
        } else {
          d2 = fminf(od1, fminf(d2, od2));
        }
      }
      if (col == 0) {
        int lr = wm * 128 + mt * 16 + quad * 4 + r;  // 0..255
        d1L[lr][wn] = d1;
        d2L[lr][wn] = d2;
        i1L[lr][wn] = i1;
      }
    }
  }
  __syncthreads();
  if (tid < 256) {
    float m1 = d1L[tid][0], m2 = d2L[tid][0];
    int mi = i1L[tid][0];
    #pragma unroll
    for (int w = 1; w < 4; w++) {
      float b1 = d1L[tid][w], b2 = d2L[tid][w];
      int bi = i1L[tid][w];
      if (b1 < m1 || (b1 == m1 && bi < mi)) { m2 = fminf(m1, b2); m1 = b1; mi = bi; }
      else { m2 = fminf(m2, fminf(b1, b2)); }
    }
    int o = bn * NTOT + bm * 256 + tid;
    ws[WS_CAND1 + o] = m1;
    ws[WS_CAND2 + o] = m2;
    ((int*)ws)[WS_CANDI + o] = mi;
  }
}

// ---------- pass2: 512 blocks x 64 rows — spread gather/write across all CUs ----------
__global__ __launch_bounds__(256) void pass2_kernel(const float* __restrict__ W,
                                                    float* __restrict__ outQ,
                                                    float* __restrict__ outIdx, float* ws) {
  __shared__ float p1L[4][64];
  __shared__ float p2L[4][64];
  __shared__ int   piL[4][64];
  __shared__ int   idx_s[64];
  int tid = threadIdx.x;
  int r0 = blockIdx.x * 64;
  int grp = tid >> 6, rl = tid & 63;
  int row = r0 + rl;
  const float* c1 = ws + WS_CAND1;
  const float* c2 = ws + WS_CAND2;
  const int* ci = (const int*)ws + WS_CANDI;
  // pair-merge slots (2*grp, 2*grp+1); only grp 0,1 hold valid data (4 slots)
  {
    int oa = (2 * grp) * NTOT + row;
    int ob = (2 * grp + 1) * NTOT + row;
    float a1 = c1[oa], a2 = c2[oa];
    int ai = ci[oa];
    float b1 = c1[ob], b2 = c2[ob];
    int bi = ci[ob];
    float m1, m2; int mi;
    if (b1 < a1 || (b1 == a1 && bi < ai)) { m1 = b1; mi = bi; m2 = fminf(a1, b2); }
    else { m1 = a1; mi = ai; m2 = fminf(a2, b1); }
    p1L[grp][rl] = m1;
    p2L[grp][rl] = m2;
    piL[grp][rl] = mi;
  }
  __syncthreads();
  if (tid < 64) {
    float m1 = p1L[0][tid], m2 = p2L[0][tid];
    int mi = piL[0][tid];
    #pragma unroll
    for (int w = 1; w < 2; w++) {
      float b1 = p1L[w][tid], b2 = p2L[w][tid];
      int bi = piL[w][tid];
      if (b1 < m1 || (b1 == m1 && bi < mi)) { m2 = fminf(m1, b2); m1 = b1; mi = bi; }
      else { m2 = fminf(m2, b1); }
    }
    int rw = r0 + tid;
    outIdx[rw] = (float)mi;
    idx_s[tid] = mi;
    int* wsI = (int*)ws;
    if (m2 - m1 < TAU) {
      int p = atomicAdd(&wsI[WS_FLAGCNT], 1);
      wsI[WS_FLAGS + p] = rw;
    }
    float partial = ws[WS_XSQ + rw] + m1;
    #pragma unroll
    for (int m = 32; m >= 1; m >>= 1) partial += __shfl_xor(partial, m);
    if (tid == 0) atomicAdd(&ws[WS_COMMIT], partial);
  }
  __syncthreads();
  int wave = tid >> 6, lane = tid & 63;
  #pragma unroll 4
  for (int i = 0; i < 16; i++) {
    int rr = wave * 16 + i;
    int ix = idx_s[rr];
    float4 v = ((const float4*)(W + (size_t)ix * DIMS))[lane];
    ((float4*)(outQ + (size_t)(r0 + rr) * DIMS))[lane] = v;
  }
}

// ---------- f64 refinement (blocks 0..511) + fused scalar finalize (block 512) ----------
__global__ __launch_bounds__(256) void refine_kernel(const float* __restrict__ X,
                                                     const float* __restrict__ W,
                                                     float* __restrict__ outQ,
                                                     float* __restrict__ outIdx, float* ws,
                                                     const float* __restrict__ U,
                                                     float* __restrict__ out) {
  __shared__ float xs[DIMS];
  __shared__ double dm[256];
  __shared__ int im[256];
  __shared__ int chosen;
  int tid = threadIdx.x;
  if (blockIdx.x == 512) {
    // ---- finalize ----
    __shared__ float red[256];
    float s = 0.f;
    for (int e = tid; e < KCODES; e += 256) s += U[e] + 1e-5f;
    red[tid] = s;
    __syncthreads();
    for (int st = 128; st >= 1; st >>= 1) {
      if (tid < st) red[tid] += red[tid + st];
      __syncthreads();
    }
    float S = red[0];
    __syncthreads();
    float denom = fmaxf(S, 1e-5f * 1024.0f);
    float h = 0.f;
    for (int e = tid; e < KCODES; e += 256) {
      float p = (U[e] + 1e-5f) / denom;
      h += p * logf(p + 1e-5f);
    }
    red[tid] = h;
    __syncthreads();
    for (int st = 128; st >= 1; st >>= 1) {
      if (tid < st) red[tid] += red[tid + st];
      __syncthreads();
    }
    float H = -red[0] / 6.93147180559945f;  // ln(1024)
    __syncthreads();
    float m = ws[WS_COLSUM + tid] * (1.0f / 1024.0f);
    float var = ws[WS_COLSQ + tid] * (1.0f / 1024.0f) - m * m;
    float r = 0.05f - var;
    red[tid] = r > 0.f ? r : 0.f;
    __syncthreads();
    for (int st = 128; st >= 1; st >>= 1) {
      if (tid < st) red[tid] += red[tid + st];
      __syncthreads();
    }
    if (tid == 0) {
      float varloss = 1e-3f * (red[0] / 256.0f);
      float gap = H < 0.5f ? (0.5f - H) : (H > 0.9f ? (H - 0.9f) : 0.0f);
      float entloss = 0.1f * gap * gap;
      float commit = 0.25f * ws[WS_COMMIT] / 8388608.0f;
      float dec = 1e-3f * ws[WS_DECORR] / 65536.0f;
      float* sc = out + OUT_SCAL;
      sc[0] = commit + entloss + varloss + dec;
      sc[1] = commit;
      sc[2] = entloss;
      sc[3] = varloss;
      sc[4] = dec;
      sc[5] = H;
    }
    return;
  }
  const int* wsI = (const int*)ws;
  int cnt = wsI[WS_FLAGCNT];
  const int* list = wsI + WS_FLAGS;
  for (int f = blockIdx.x; f < cnt; f += 512) {
    int row = list[f];
    __syncthreads();
    if (tid < 64) ((float4*)xs)[tid] = ((const float4*)(X + (size_t)row * DIMS))[tid];
    __syncthreads();
    double bd = 1.0e300;
    int bi = 0;
    for (int jj = 0; jj < 4; jj++) {
      int c = tid + 256 * jj;
      double a0 = 0.0, a1 = 0.0, a2 = 0.0, a3 = 0.0;
      const float* wr = W + (size_t)c * DIMS;
      #pragma unroll 4
      for (int d4 = 0; d4 < 64; d4++) {
        float4 w = ((const float4*)wr)[d4];
        float4 x = ((const float4*)xs)[d4];
        double e0 = (double)x.x - (double)w.x;
        double e1 = (double)x.y - (double)w.y;
        double e2 = (double)x.z - (double)w.z;
        double e3 = (double)x.w - (double)w.w;
        a0 += e0 * e0; a1 += e1 * e1; a2 += e2 * e2; a3 += e3 * e3;
      }
      double s = (a0 + a1) + (a2 + a3);
      if (s < bd) { bd = s; bi = c; }
    }
    dm[tid] = bd; im[tid] = bi;
    __syncthreads();
    for (int st = 128; st >= 1; st >>= 1) {
      if (tid < st) {
        if (dm[tid + st] < dm[tid] || (dm[tid + st] == dm[tid] && im[tid + st] < im[tid])) {
          dm[tid] = dm[tid + st]; im[tid] = im[tid + st];
        }
      }
      __syncthreads();
    }
    if (tid == 0) { chosen = im[0]; outIdx[row] = (float)im[0]; }
    __syncthreads();
    int ix = chosen;
    if (tid < 64)
      ((float4*)(outQ + (size_t)row * DIMS))[tid] = ((const float4*)(W + (size_t)ix * DIMS))[tid];
  }
}

extern "C" void kernel_launch(void* const* d_in, const int* in_sizes, int n_in, void* d_out,
                              int out_size, void* d_ws, size_t ws_size, hipStream_t stream) {
  const float* X = (const float*)d_in[0];
  const float* W = (const float*)d_in[1];
  const float* U = (const float*)d_in[2];
  float* out = (float*)d_out;
  float* ws = (float*)d_ws;
  __bf16* Xp = (__bf16*)(out + OUT_Q);       // 33.55 MB, overwritten by pass2's gather
  __bf16* Wp2 = (__bf16*)(ws + WS_WP);       // 1 MB, fragment-ordered

  hipMemsetAsync(d_ws, 0, 12, stream);       // COMMIT, FLAGCNT, DECORR only
  prep_kernel<<<1312, 256, 0, stream>>>(X, W, Xp, Wp2, ws);
  pass1_kernel<<<512, 512, 0, stream>>>(Xp, Wp2, ws);
  pass2_kernel<<<512, 256, 0, stream>>>(W, out + OUT_Q, out + OUT_IDX, ws);
  refine_kernel<<<513, 256, 0, stream>>>(X, W, out + OUT_Q, out + OUT_IDX, ws, U, out);
}

// Round 8
// 219.756 us; speedup vs baseline: 1.1101x; 1.1101x over previous
//
#include <hip/hip_runtime.h>
#include <math.h>

#define DIMS   256
#define KCODES 1024
#define NTOT   32768
#define TAU    4.0e-4f   // 3-term split distance-compare error <~6e-5; 6x margin

typedef __bf16 bf16x8 __attribute__((ext_vector_type(8)));
typedef float  f32x4  __attribute__((ext_vector_type(4)));

// ---- workspace layout (float indices; int views share) ----
#define WS_COMMIT   0          // float atomic
#define WS_FLAGCNT  1          // int atomic
#define WS_DECORR   2          // float atomic
#define WS_COLSUM   16         // float[256]  (direct-stored by cov blocks)
#define WS_COLSQ    272        // float[256]  (direct-stored by cov blocks)
#define WS_WSQ      1024       // float[1024]  (direct-stored by W-pack blocks)
#define WS_XSQ      2048       // float[32768] (direct-stored by X-pack blocks)
// memset zero region: bytes [0, 12) only (COMMIT, FLAGCNT, DECORR)
#define WS_FLAGS    34816      // int[32768]
#define WS_CAND1    67584      // float[8*32768]
#define WS_CAND2    329728     // float[8*32768]
#define WS_CANDI    591872     // int[8*32768]
#define WS_WP       854016     // bf16[524288] = 1 MB, fragment-ordered W

// ---- output layout (floats) ----
#define OUT_Q    0
#define OUT_IDX  8388608
#define OUT_SCAL 8421376

// Fragment layout (both Xp and Wp2), bf16 elems:
//   frag(bt, kt, wv, t, hl) base = ((((bt*8+kt)*2+wv)*4+t)*2+hl)*512
//   element (lane = kq*16+lc, e) at base + lane*8 + e
//   holds hi/lo bf16 of src[row = bt*128+wv*64+t*16+lc][k = kt*32+kq*8+e]
// => for fixed (bt,kt) the 16 frags are 8192 contiguous elems (16 KB).

// ---------- fused prep ----------
// blocks [0,1024): pack X | [1024,1056): pack W | [1056,1312): cov+colstats
__global__ __launch_bounds__(256) void prep_kernel(const float* __restrict__ X,
                                                   const float* __restrict__ W,
                                                   __bf16* __restrict__ Xp,
                                                   __bf16* __restrict__ Wp2,
                                                   float* ws) {
  int b = blockIdx.x;
  int tid = threadIdx.x;
  if (b < 1056) {
    __shared__ float sqred[256];
    bool isW = b >= 1024;
    const float* src = isW ? W : X;
    __bf16* dst = isW ? Wp2 : Xp;
    int sqoff = isW ? WS_WSQ : WS_XSQ;
    int bb = isW ? b - 1024 : b;
    int kt = tid >> 5, mtl = (tid >> 4) & 1, lc = tid & 15;
    int row = bb * 32 + mtl * 16 + lc;
    int bt = row >> 7, c = row & 127;
    int wv = c >> 6, t = (c >> 4) & 3;
    size_t hibase = ((((size_t)(bt * 8 + kt) * 2 + wv) * 4 + t) * 2) * 512;
    const float* s = src + (size_t)row * DIMS + kt * 32;
    float sq = 0.f;
    #pragma unroll
    for (int kq = 0; kq < 4; kq++) {
      float4 u = *(const float4*)(s + kq * 8);
      float4 v = *(const float4*)(s + kq * 8 + 4);
      float f[8] = {u.x, u.y, u.z, u.w, v.x, v.y, v.z, v.w};
      bf16x8 hi, lo;
      #pragma unroll
      for (int e = 0; e < 8; e++) {
        __bf16 h = (__bf16)f[e];
        hi[e] = h;
        lo[e] = (__bf16)(f[e] - (float)h);
        sq = fmaf(f[e], f[e], sq);
      }
      size_t off = (size_t)(kq * 16 + lc) * 8;
      *(bf16x8*)&dst[hibase + off] = hi;
      *(bf16x8*)&dst[hibase + 512 + off] = lo;
    }
    // block-owned row-norm reduce (rows bb*32..bb*32+31)
    sqred[tid] = sq;
    __syncthreads();
    if (tid < 32) {
      float s8 = 0.f;
      #pragma unroll
      for (int k = 0; k < 8; k++) s8 += sqred[k * 32 + tid];
      ws[sqoff + bb * 32 + tid] = s8;
    }
  } else {
    // cov + colstats: 256 blocks x 1 column, self-contained means
    __shared__ float wi_s[KCODES];
    __shared__ float red2[256];
    __shared__ float miB;
    __shared__ float red[4];
    int i0 = b - 1056;
    #pragma unroll
    for (int q = 0; q < 4; q++) {
      int row = q * 256 + tid;
      wi_s[row] = W[(size_t)row * DIMS + i0];
    }
    __syncthreads();
    float pm = 0.f;
    #pragma unroll
    for (int q = 0; q < 4; q++) pm += wi_s[tid * 4 + q];
    red2[tid] = pm;
    __syncthreads();
    if (tid == 0) {
      float s = 0.f;
      for (int k = 0; k < 256; k++) s += red2[k];
      miB = s * (1.0f / 1024.0f);
    }
    int j = tid;
    float a0 = 0.f, sj = 0.f, sqj = 0.f;
    for (int k = 0; k < KCODES; k += 4) {
      #pragma unroll
      for (int u = 0; u < 4; u++) {
        float wj = W[(size_t)(k + u) * DIMS + j];
        a0 = fmaf(wi_s[k + u], wj, a0);
        sj += wj;
        sqj = fmaf(wj, wj, sqj);
      }
    }
    if (j == i0) {
      ws[WS_COLSUM + i0] = sj;
      ws[WS_COLSQ + i0] = sqj;
    }
    __syncthreads();  // miB ready
    const float inv = 1.0f / 1024.0f;
    float mj = sj * inv;
    float v = 0.f;
    float c0 = a0 * inv - miB * mj;
    if (i0 != j) v = c0 * c0;
    #pragma unroll
    for (int m = 32; m >= 1; m >>= 1) v += __shfl_xor(v, m);
    if ((j & 63) == 0) red[j >> 6] = v;
    __syncthreads();
    if (j == 0) atomicAdd(&ws[WS_DECORR], (red[0] + red[1]) + (red[2] + red[3]));
  }
}

// ---------- pass1 v8: v5 skeleton re-partitioned for occupancy ----------
// THEORY: v5 (72.7us) is latency-bound at ~2 waves/SIMD (MfmaUtil=VALUBusy=Occ
// =27-29%; per-SIMD busy-cycle totals are 5x under the wall). v5's ~180-reg
// footprint (64 AGPR acc + operands) caps occupancy. v8 keeps the SAME proven
// single-buffer 2-barrier kt-loop and 128x128 tile but splits it across 8
// half-size waves: acc[2][4] = 32 AGPR, ~110 regs total ->
// __launch_bounds__(512,4) = 2 blocks/CU = 4 waves/SIMD (2x v5). Per-wave MFMA
// and epilogue halve; twice the waves hide the stage/barrier latency (G1+m114).
// Numerics: per-acc MFMA chain identical (kt ascending; hi*hi, hi*lo, lo*hi)
// -> bit-identical. Cand layout: 8 slots (grid 2048), pass2 = R4's 8-slot merge.
__device__ __forceinline__ void stage16(const __bf16* g, __bf16* l) {
  __builtin_amdgcn_global_load_lds(
      (const __attribute__((address_space(1))) void*)g,
      (__attribute__((address_space(3))) void*)l, 16, 0, 0);
}

__global__ __launch_bounds__(512, 4) void pass1_kernel(const __bf16* __restrict__ Xp,
                                                       const __bf16* __restrict__ Wp2,
                                                       float* ws) {
  __shared__ __align__(16) __bf16 buf[16384];  // A: [0,8192), B: [8192,16384) — 32 KB
  __shared__ float wsqs[128];
  __shared__ float d1L[256];
  __shared__ float d2L[256];
  __shared__ int   i1L[256];

  int tid = threadIdx.x;
  int lane = tid & 63, wave = tid >> 6;   // 8 waves
  int wm = wave >> 1, wn = wave & 1;      // wm: 32-row strip 0..3, wn: 64-col strip 0..1
  int quad = lane >> 4, col = lane & 15;
  int l = blockIdx.x;
  // L2-window swizzle (R4): XCD x runs j=0..255; first 128 j's span 16bm x 8bn
  int x = l & 7;
  int j = l >> 3;
  int bm = x * 32 + (j & 15) + (j >> 7) * 16;   // 0..255
  int bn = (j >> 4) & 7;                        // 0..7
  int rowBase = bm * 128, cb = bn * 128;

  if (tid < 128) wsqs[tid] = ws[WS_WSQ + cb + tid];

  f32x4 acc[2][4];
  #pragma unroll
  for (int i = 0; i < 2; i++)
    #pragma unroll
    for (int jj = 0; jj < 4; jj++) acc[i][jj] = (f32x4){0.f, 0.f, 0.f, 0.f};

  const __bf16* aSrc = Xp + (size_t)bm * 65536;   // + kt*8192
  const __bf16* bSrc = Wp2 + (size_t)bn * 65536;

  // A frag base for this wave: rows wm*32+mt*16+lc -> frag ((wm>>1)*4+(wm&1)*2+mt)*2+hl
  const int aFragBase = ((wm >> 1) * 8 + (wm & 1) * 4) * 512;

  #pragma unroll
  for (int kt = 0; kt < 8; kt++) {
    __syncthreads();  // all reads of buf (previous kt) complete
    // stage kt tile: 512 threads x 4 x 16B = 32 KB (A 16 KB + B 16 KB)
    stage16(aSrc + kt * 8192 + tid * 8, buf + tid * 8);
    stage16(aSrc + kt * 8192 + 4096 + tid * 8, buf + 4096 + tid * 8);
    stage16(bSrc + kt * 8192 + tid * 8, buf + 8192 + tid * 8);
    stage16(bSrc + kt * 8192 + 4096 + tid * 8, buf + 12288 + tid * 8);
    __syncthreads();  // compiler drains vmcnt before barrier -> staged data visible

    const __bf16* bA = buf + aFragBase + lane * 8;
    const __bf16* bB = buf + 8192 + wn * 4096 + lane * 8;
    bf16x8 Bf[4][2];
    #pragma unroll
    for (int nt = 0; nt < 4; nt++) {
      Bf[nt][0] = *(const bf16x8*)(bB + nt * 1024);
      Bf[nt][1] = *(const bf16x8*)(bB + nt * 1024 + 512);
    }
    #pragma unroll
    for (int mt = 0; mt < 2; mt++) {
      bf16x8 A0 = *(const bf16x8*)(bA + mt * 1024);
      bf16x8 A1 = *(const bf16x8*)(bA + mt * 1024 + 512);
      #pragma unroll
      for (int nt = 0; nt < 4; nt++) {
        acc[mt][nt] = __builtin_amdgcn_mfma_f32_16x16x32_bf16(A0, Bf[nt][0], acc[mt][nt], 0, 0, 0);
        acc[mt][nt] = __builtin_amdgcn_mfma_f32_16x16x32_bf16(A0, Bf[nt][1], acc[mt][nt], 0, 0, 0);
        acc[mt][nt] = __builtin_amdgcn_mfma_f32_16x16x32_bf16(A1, Bf[nt][0], acc[mt][nt], 0, 0, 0);
      }
    }
  }
  __syncthreads();  // wsqs + buf quiesce before epilogue

  // epilogue: per-row (best, 2nd, idx); C layout: row = quad*4 + reg, col = lane&15
  #pragma unroll
  for (int mt = 0; mt < 2; mt++) {
    #pragma unroll
    for (int r = 0; r < 4; r++) {
      float d1 = 3.0e38f, d2 = 3.0e38f;
      int i1 = 0;
      #pragma unroll
      for (int nt = 0; nt < 4; nt++) {
        int lc = wn * 64 + nt * 16 + col;
        float d = wsqs[lc] - 2.0f * acc[mt][nt][r];
        int g = cb + lc;
        if (d < d1) { d2 = d1; d1 = d; i1 = g; }
        else if (d < d2) d2 = d;
      }
      #pragma unroll
      for (int m = 1; m < 16; m <<= 1) {
        float od1 = __shfl_xor(d1, m);
        int oi1 = __shfl_xor(i1, m);
        float od2 = __shfl_xor(d2, m);
        if (od1 < d1 || (od1 == d1 && oi1 < i1)) {
          d2 = fminf(d1, fminf(d2, od2));
          d1 = od1; i1 = oi1;
        } else {
          d2 = fminf(od1, fminf(d2, od2));
        }
      }
      if (col == 0) {
        int lr = wm * 32 + mt * 16 + quad * 4 + r;   // 0..127
        d1L[lr * 2 + wn] = d1;
        d2L[lr * 2 + wn] = d2;
        i1L[lr * 2 + wn] = i1;
      }
    }
  }
  __syncthreads();
  if (tid < 128) {
    float a1 = d1L[tid * 2], a2 = d2L[tid * 2];
    int ai = i1L[tid * 2];
    float b1 = d1L[tid * 2 + 1], b2 = d2L[tid * 2 + 1];
    int bi = i1L[tid * 2 + 1];
    float m1, m2; int mi;
    if (b1 < a1 || (b1 == a1 && bi < ai)) { m1 = b1; mi = bi; m2 = fminf(a1, b2); }
    else { m1 = a1; mi = ai; m2 = fminf(b1, a2); }
    int o = bn * NTOT + rowBase + tid;
    ws[WS_CAND1 + o] = m1;
    ws[WS_CAND2 + o] = m2;
    ((int*)ws)[WS_CANDI + o] = mi;
  }
}

// ---------- pass2: 512 blocks x 64 rows — merge 8 slots, gather/write ----------
__global__ __launch_bounds__(256) void pass2_kernel(const float* __restrict__ W,
                                                    float* __restrict__ outQ,
                                                    float* __restrict__ outIdx, float* ws) {
  __shared__ float p1L[4][64];
  __shared__ float p2L[4][64];
  __shared__ int   piL[4][64];
  __shared__ int   idx_s[64];
  int tid = threadIdx.x;
  int r0 = blockIdx.x * 64;
  int grp = tid >> 6, rl = tid & 63;
  int row = r0 + rl;
  const float* c1 = ws + WS_CAND1;
  const float* c2 = ws + WS_CAND2;
  const int* ci = (const int*)ws + WS_CANDI;
  // pair-merge slots (2*grp, 2*grp+1)
  {
    int oa = (2 * grp) * NTOT + row;
    int ob = (2 * grp + 1) * NTOT + row;
    float a1 = c1[oa], a2 = c2[oa];
    int ai = ci[oa];
    float b1 = c1[ob], b2 = c2[ob];
    int bi = ci[ob];
    float m1, m2; int mi;
    if (b1 < a1 || (b1 == a1 && bi < ai)) { m1 = b1; mi = bi; m2 = fminf(a1, b2); }
    else { m1 = a1; mi = ai; m2 = fminf(a2, b1); }
    p1L[grp][rl] = m1;
    p2L[grp][rl] = m2;
    piL[grp][rl] = mi;
  }
  __syncthreads();
  if (tid < 64) {
    float m1 = p1L[0][tid], m2 = p2L[0][tid];
    int mi = piL[0][tid];
    #pragma unroll
    for (int w = 1; w < 4; w++) {
      float b1 = p1L[w][tid], b2 = p2L[w][tid];
      int bi = piL[w][tid];
      if (b1 < m1 || (b1 == m1 && bi < mi)) { m2 = fminf(m1, b2); m1 = b1; mi = bi; }
      else { m2 = fminf(m2, b1); }
    }
    int rw = r0 + tid;
    outIdx[rw] = (float)mi;
    idx_s[tid] = mi;
    int* wsI = (int*)ws;
    if (m2 - m1 < TAU) {
      int p = atomicAdd(&wsI[WS_FLAGCNT], 1);
      wsI[WS_FLAGS + p] = rw;
    }
    float partial = ws[WS_XSQ + rw] + m1;
    #pragma unroll
    for (int m = 32; m >= 1; m >>= 1) partial += __shfl_xor(partial, m);
    if (tid == 0) atomicAdd(&ws[WS_COMMIT], partial);
  }
  __syncthreads();
  int wave = tid >> 6, lane = tid & 63;
  #pragma unroll 4
  for (int i = 0; i < 16; i++) {
    int rr = wave * 16 + i;
    int ix = idx_s[rr];
    float4 v = ((const float4*)(W + (size_t)ix * DIMS))[lane];
    ((float4*)(outQ + (size_t)(r0 + rr) * DIMS))[lane] = v;
  }
}

// ---------- f64 refinement (blocks 0..511) + fused scalar finalize (block 512) ----------
__global__ __launch_bounds__(256) void refine_kernel(const float* __restrict__ X,
                                                     const float* __restrict__ W,
                                                     float* __restrict__ outQ,
                                                     float* __restrict__ outIdx, float* ws,
                                                     const float* __restrict__ U,
                                                     float* __restrict__ out) {
  __shared__ float xs[DIMS];
  __shared__ double dm[256];
  __shared__ int im[256];
  __shared__ int chosen;
  int tid = threadIdx.x;
  if (blockIdx.x == 512) {
    // ---- finalize ----
    __shared__ float red[256];
    float s = 0.f;
    for (int e = tid; e < KCODES; e += 256) s += U[e] + 1e-5f;
    red[tid] = s;
    __syncthreads();
    for (int st = 128; st >= 1; st >>= 1) {
      if (tid < st) red[tid] += red[tid + st];
      __syncthreads();
    }
    float S = red[0];
    __syncthreads();
    float denom = fmaxf(S, 1e-5f * 1024.0f);
    float h = 0.f;
    for (int e = tid; e < KCODES; e += 256) {
      float p = (U[e] + 1e-5f) / denom;
      h += p * logf(p + 1e-5f);
    }
    red[tid] = h;
    __syncthreads();
    for (int st = 128; st >= 1; st >>= 1) {
      if (tid < st) red[tid] += red[tid + st];
      __syncthreads();
    }
    float H = -red[0] / 6.93147180559945f;  // ln(1024)
    __syncthreads();
    float m = ws[WS_COLSUM + tid] * (1.0f / 1024.0f);
    float var = ws[WS_COLSQ + tid] * (1.0f / 1024.0f) - m * m;
    float r = 0.05f - var;
    red[tid] = r > 0.f ? r : 0.f;
    __syncthreads();
    for (int st = 128; st >= 1; st >>= 1) {
      if (tid < st) red[tid] += red[tid + st];
      __syncthreads();
    }
    if (tid == 0) {
      float varloss = 1e-3f * (red[0] / 256.0f);
      float gap = H < 0.5f ? (0.5f - H) : (H > 0.9f ? (H - 0.9f) : 0.0f);
      float entloss = 0.1f * gap * gap;
      float commit = 0.25f * ws[WS_COMMIT] / 8388608.0f;
      float dec = 1e-3f * ws[WS_DECORR] / 65536.0f;
      float* sc = out + OUT_SCAL;
      sc[0] = commit + entloss + varloss + dec;
      sc[1] = commit;
      sc[2] = entloss;
      sc[3] = varloss;
      sc[4] = dec;
      sc[5] = H;
    }
    return;
  }
  const int* wsI = (const int*)ws;
  int cnt = wsI[WS_FLAGCNT];
  const int* list = wsI + WS_FLAGS;
  for (int f = blockIdx.x; f < cnt; f += 512) {
    int row = list[f];
    __syncthreads();
    if (tid < 64) ((float4*)xs)[tid] = ((const float4*)(X + (size_t)row * DIMS))[tid];
    __syncthreads();
    double bd = 1.0e300;
    int bi = 0;
    for (int jj = 0; jj < 4; jj++) {
      int c = tid + 256 * jj;
      double a0 = 0.0, a1 = 0.0, a2 = 0.0, a3 = 0.0;
      const float* wr = W + (size_t)c * DIMS;
      #pragma unroll 4
      for (int d4 = 0; d4 < 64; d4++) {
        float4 w = ((const float4*)wr)[d4];
        float4 x = ((const float4*)xs)[d4];
        double e0 = (double)x.x - (double)w.x;
        double e1 = (double)x.y - (double)w.y;
        double e2 = (double)x.z - (double)w.z;
        double e3 = (double)x.w - (double)w.w;
        a0 += e0 * e0; a1 += e1 * e1; a2 += e2 * e2; a3 += e3 * e3;
      }
      double s = (a0 + a1) + (a2 + a3);
      if (s < bd) { bd = s; bi = c; }
    }
    dm[tid] = bd; im[tid] = bi;
    __syncthreads();
    for (int st = 128; st >= 1; st >>= 1) {
      if (tid < st) {
        if (dm[tid + st] < dm[tid] || (dm[tid + st] == dm[tid] && im[tid + st] < im[tid])) {
          dm[tid] = dm[tid + st]; im[tid] = im[tid + st];
        }
      }
      __syncthreads();
    }
    if (tid == 0) { chosen = im[0]; outIdx[row] = (float)im[0]; }
    __syncthreads();
    int ix = chosen;
    if (tid < 64)
      ((float4*)(outQ + (size_t)row * DIMS))[tid] = ((const float4*)(W + (size_t)ix * DIMS))[tid];
  }
}

extern "C" void kernel_launch(void* const* d_in, const int* in_sizes, int n_in, void* d_out,
                              int out_size, void* d_ws, size_t ws_size, hipStream_t stream) {
  const float* X = (const float*)d_in[0];
  const float* W = (const float*)d_in[1];
  const float* U = (const float*)d_in[2];
  float* out = (float*)d_out;
  float* ws = (float*)d_ws;
  __bf16* Xp = (__bf16*)(out + OUT_Q);       // 33.55 MB, overwritten by pass2's gather
  __bf16* Wp2 = (__bf16*)(ws + WS_WP);       // 1 MB, fragment-ordered

  hipMemsetAsync(d_ws, 0, 12, stream);       // COMMIT, FLAGCNT, DECORR only
  prep_kernel<<<1312, 256, 0, stream>>>(X, W, Xp, Wp2, ws);
  pass1_kernel<<<2048, 512, 0, stream>>>(Xp, Wp2, ws);
  pass2_kernel<<<512, 256, 0, stream>>>(W, out + OUT_Q, out + OUT_IDX, ws);
  refine_kernel<<<513, 256, 0, stream>>>(X, W, out + OUT_Q, out + OUT_IDX, ws, U, out);
}